// Round 12
// baseline (259.777 us; speedup 1.0000x reference)
//
#include <hip/hip_runtime.h>
#include <stdint.h>

typedef _Float16 half4v __attribute__((ext_vector_type(4)));
typedef _Float16 half8v __attribute__((ext_vector_type(8)));
typedef float    f32x4  __attribute__((ext_vector_type(4)));
typedef __attribute__((address_space(3))) void       lds_void;
typedef const __attribute__((address_space(1))) void g_void;

#define NB 8
#define SXX 2048
#define DD 512
#define QBLK 64
#define TBLK 32
#define NITER 64

/* y tiles: 3 buffers of 32 rows x 1040 B (row bank-rotate 4). */
#define RSB 1040u
#define YSZ (32u * RSB)            /* 33280 */
#define POFF (3u * YSZ)            /* 99840: P[64 q][32 t] fp16, row 72 B, x2 */
#define PR 72u
#define PSZ (64u * PR)             /* 4608 */
#define SCOFF (POFF + 2u * PSZ)    /* 109056: per-q scale f32[64] x2 */
#define LIOFF (SCOFF + 512u)       /* 109568: per-q 1/l f32[64] */
#define LDS_BYTES 109824
#define YH_BYTES (8ull * 2048ull * 512ull * 2ull)   /* 16 MiB fp16 y */

__global__ __launch_bounds__(256)
void convert_y(const float* __restrict__ y, _Float16* __restrict__ yh) {
  const int i = (blockIdx.x * 256 + threadIdx.x) * 8;
  f32x4 f0 = *(const f32x4*)(y + i);
  f32x4 f1 = *(const f32x4*)(y + i + 4);
  half8v h;
  h[0]=(_Float16)f0[0]; h[1]=(_Float16)f0[1]; h[2]=(_Float16)f0[2]; h[3]=(_Float16)f0[3];
  h[4]=(_Float16)f1[0]; h[5]=(_Float16)f1[1]; h[6]=(_Float16)f1[2]; h[7]=(_Float16)f1[3];
  *(half8v*)(yh + i) = h;
}

template <bool USE_WS>
__global__ __launch_bounds__(512)
__attribute__((amdgpu_waves_per_eu(2, 2)))   /* pin 2 waves/EU: 256-VGPR budget, stop heuristic spill */
void attn_fused(const float* __restrict__ x, const float* __restrict__ y,
                const _Float16* __restrict__ yh, float* __restrict__ out) {
  extern __shared__ char smem[];
  const int bid   = blockIdx.x;
  const int b     = bid & 7;      /* one batch per XCD */
  const int qtile = bid >> 3;
  const int tid   = threadIdx.x;
  const int w     = tid >> 6;     /* 0..7; w<2 = producers */
  const int lane  = tid & 63;
  const int l15   = lane & 15;
  const int g     = lane >> 4;

  const float*    xb  = x + (size_t)b * SXX * DD;
  const float*    yb  = y + (size_t)b * SXX * DD;
  const _Float16* yhb = USE_WS ? (yh + (size_t)b * SXX * DD) : nullptr;
  float* outb = out + (size_t)b * SXX * (2 * DD);
  const int qbase = qtile * QBLK;

  /* stage tile 0: all 8 waves, 4 rows each */
  if (USE_WS) {
#pragma unroll
    for (int i = 0; i < 4; ++i) {
      const int row = w * 4 + i;
      __builtin_amdgcn_global_load_lds((g_void*)(yhb + row * DD + lane * 8),
                                       (lds_void*)(smem + (uint32_t)row * RSB), 16, 0, 0);
    }
  }

  /* out[:, :512] = x (exact fp32 copy) */
  {
    const f32x4* src = (const f32x4*)(xb + (size_t)qbase * DD);
    for (int i = tid; i < QBLK * (DD / 4); i += 512) {
      f32x4 v = src[i];
      *(f32x4*)(outb + (size_t)(qbase + (i >> 7)) * (2 * DD) + (i & 127) * 4) = v;
    }
  }

  /* producers: Q fragments for 32 q (2 qh-subtiles), B-operand layout
     (lane: col q = qbase + w*32 + qh*16 + l15, elems d = 32c + 8g + j) */
  half8v bq0[16], bq1[16];
  if (w < 2) {
    const float* xr0 = xb + (size_t)(qbase + w * 32 + l15) * DD;
    const float* xr1 = xr0 + 16 * DD;
#pragma unroll
    for (int c = 0; c < 16; ++c) {
      const int d0 = c * 32 + g * 8;
      f32x4 f0 = *(const f32x4*)(xr0 + d0);
      f32x4 f1 = *(const f32x4*)(xr0 + d0 + 4);
      half8v h;
      h[0]=(_Float16)f0[0]; h[1]=(_Float16)f0[1]; h[2]=(_Float16)f0[2]; h[3]=(_Float16)f0[3];
      h[4]=(_Float16)f1[0]; h[5]=(_Float16)f1[1]; h[6]=(_Float16)f1[2]; h[7]=(_Float16)f1[3];
      bq0[c] = h;
      f0 = *(const f32x4*)(xr1 + d0);
      f1 = *(const f32x4*)(xr1 + d0 + 4);
      h[0]=(_Float16)f0[0]; h[1]=(_Float16)f0[1]; h[2]=(_Float16)f0[2]; h[3]=(_Float16)f0[3];
      h[4]=(_Float16)f1[0]; h[5]=(_Float16)f1[1]; h[6]=(_Float16)f1[2]; h[7]=(_Float16)f1[3];
      bq1[c] = h;
    }
  }

  if (!USE_WS && w >= 2) {
#pragma unroll
    for (int i = 0; i < 6; ++i) {
      const int row = (w - 2) + 6 * i;
      if (row < 32) {
        const float* p = yb + row * DD + lane * 8;
        f32x4 f0 = *(const f32x4*)p, f1 = *(const f32x4*)(p + 4);
        half8v h;
        h[0]=(_Float16)f0[0]; h[1]=(_Float16)f0[1]; h[2]=(_Float16)f0[2]; h[3]=(_Float16)f0[3];
        h[4]=(_Float16)f1[0]; h[5]=(_Float16)f1[1]; h[6]=(_Float16)f1[2]; h[7]=(_Float16)f1[3];
        *(half8v*)(smem + (uint32_t)row * RSB + (uint32_t)lane * 16u) = h;
      }
    }
  }

  f32x4 acc[4][4];   /* [qq][dtl]: a[qbase+qq*16+4g+r][w*64+dtl*16+l15] */
#pragma unroll
  for (int i = 0; i < 4; ++i)
#pragma unroll
    for (int j = 0; j < 4; ++j) acc[i][j] = (f32x4){0.f, 0.f, 0.f, 0.f};
  float mrun0 = -3.0e38f, mrun1 = -3.0e38f, lrun0 = 0.0f, lrun1 = 0.0f;

  __syncthreads();

  /* PV for tile with buffers (ybo = y buf offset, pbo = P buf, sco = scale) */
  auto pv_step = [&](uint32_t ybo, uint32_t pbo, uint32_t sco) {
#pragma unroll
    for (int qq = 0; qq < 4; ++qq) {
      const f32x4 s4 = *(const f32x4*)(smem + sco + (uint32_t)(qq * 16 + 4 * g) * 4u);
#pragma unroll
      for (int dtl = 0; dtl < 4; ++dtl) {
        acc[qq][dtl][0] *= s4[0]; acc[qq][dtl][1] *= s4[1];
        acc[qq][dtl][2] *= s4[2]; acc[qq][dtl][3] *= s4[3];
      }
    }
    __builtin_amdgcn_sched_barrier(0);
    /* P A-frags: rows qq*16+l15, cols {4g+j, 16+4g+j} */
    half4v palo[4], pahi[4];
#pragma unroll
    for (int qq = 0; qq < 4; ++qq) {
      const uint32_t a = pbo + (uint32_t)(qq * 16 + l15) * PR + (uint32_t)g * 8u;
      asm volatile("ds_read_b64 %0, %1" : "=v"(palo[qq]) : "v"(a));
      asm volatile("ds_read_b64 %0, %1" : "=v"(pahi[qq]) : "v"(a + 32u));
    }
    asm volatile("s_waitcnt lgkmcnt(0)" ::: "memory");
    __builtin_amdgcn_sched_barrier(0);
    half8v pa8[4];
#pragma unroll
    for (int qq = 0; qq < 4; ++qq)
      pa8[qq] = __builtin_shufflevector(palo[qq], pahi[qq], 0, 1, 2, 3, 4, 5, 6, 7);
    /* V B-frags via positional tr-read, 1-ahead counted pipeline (tr-only window) */
    const uint32_t tb = ybo + (uint32_t)(4 * g + (l15 >> 2)) * RSB +
                        (uint32_t)(l15 & 3) * 8u + (uint32_t)w * 128u;
    half4v blo[2], bhi[2];
    asm volatile("ds_read_b64_tr_b16 %0, %1" : "=v"(blo[0]) : "v"(tb));
    asm volatile("ds_read_b64_tr_b16 %0, %1" : "=v"(bhi[0]) : "v"(tb + 16u * RSB));
#pragma unroll
    for (int dtl = 0; dtl < 4; ++dtl) {
      const int cur = dtl & 1, nxt = cur ^ 1;
      if (dtl < 3) {
        const uint32_t a2 = tb + (uint32_t)(dtl + 1) * 32u;
        asm volatile("ds_read_b64_tr_b16 %0, %1" : "=v"(blo[nxt]) : "v"(a2));
        asm volatile("ds_read_b64_tr_b16 %0, %1" : "=v"(bhi[nxt]) : "v"(a2 + 16u * RSB));
        asm volatile("s_waitcnt lgkmcnt(2)" ::: "memory");
      } else {
        asm volatile("s_waitcnt lgkmcnt(0)" ::: "memory");
      }
      __builtin_amdgcn_sched_barrier(0);
      const half8v b8 = __builtin_shufflevector(blo[cur], bhi[cur], 0, 1, 2, 3, 4, 5, 6, 7);
#pragma unroll
      for (int qq = 0; qq < 4; ++qq)
        acc[qq][dtl] = __builtin_amdgcn_mfma_f32_16x16x32_f16(pa8[qq], b8, acc[qq][dtl], 0, 0, 0);
    }
  };

  for (int it = 0; it < NITER; ++it) {
    const uint32_t yb_cur  = (uint32_t)(it % 3) * YSZ;
    const uint32_t yb_prev = (uint32_t)((it + 2) % 3) * YSZ;
    const uint32_t yb_next = (uint32_t)((it + 1) % 3) * YSZ;
    const uint32_t pb_cur  = POFF + (uint32_t)(it & 1) * PSZ;
    const uint32_t pb_prev = POFF + (uint32_t)((it + 1) & 1) * PSZ;
    const uint32_t sc_cur  = SCOFF + (uint32_t)(it & 1) * 256u;
    const uint32_t sc_prev = SCOFF + (uint32_t)((it + 1) & 1) * 256u;

    /* stage tile it+1 (all waves, async) */
    if (USE_WS && it + 1 < NITER) {
      const _Float16* src = yhb + (size_t)(it + 1) * TBLK * DD;
#pragma unroll
      for (int i = 0; i < 4; ++i) {
        const int row = w * 4 + i;
        __builtin_amdgcn_global_load_lds((g_void*)(src + row * DD + lane * 8),
                                         (lds_void*)(smem + yb_next + (uint32_t)row * RSB), 16, 0, 0);
      }
    }

    /* producers: QK(it) + full-t softmax + P/scale write */
    if (w < 2) {
      f32x4 st00 = (f32x4){0,0,0,0}, st01 = (f32x4){0,0,0,0};
      f32x4 st10 = (f32x4){0,0,0,0}, st11 = (f32x4){0,0,0,0};
#pragma unroll
      for (int c = 0; c < 16; ++c) {
        const uint32_t db = yb_cur + 64u * (uint32_t)c + 16u * (uint32_t)g;
        const half8v af0 = *(const half8v*)(smem + (uint32_t)l15 * RSB + db);
        st00 = __builtin_amdgcn_mfma_f32_16x16x32_f16(af0, bq0[c], st00, 0, 0, 0);
        st10 = __builtin_amdgcn_mfma_f32_16x16x32_f16(af0, bq1[c], st10, 0, 0, 0);
        const half8v af1 = *(const half8v*)(smem + (uint32_t)(16 + l15) * RSB + db);
        st01 = __builtin_amdgcn_mfma_f32_16x16x32_f16(af1, bq0[c], st01, 0, 0, 0);
        st11 = __builtin_amdgcn_mfma_f32_16x16x32_f16(af1, bq1[c], st11, 0, 0, 0);
      }
      /* softmax qh0 (q = w*32 + l15): S rows t = tt*16 + 4g + r, col q = l15 */
      {
        float tm = -3.0e38f;
#pragma unroll
        for (int r = 0; r < 4; ++r) tm = fmaxf(tm, fmaxf(st00[r], st01[r]));
        tm = fmaxf(tm, __shfl_xor(tm, 16));
        tm = fmaxf(tm, __shfl_xor(tm, 32));
        const float mnew = fmaxf(mrun0, tm);
        float rsum = 0.f;
        half4v h0, h1;
#pragma unroll
        for (int r = 0; r < 4; ++r) {
          const float e0 = __expf(st00[r] - mnew); rsum += e0; h0[r] = (_Float16)e0;
          const float e1 = __expf(st01[r] - mnew); rsum += e1; h1[r] = (_Float16)e1;
        }
        rsum += __shfl_xor(rsum, 16);
        rsum += __shfl_xor(rsum, 32);
        const float sc = __expf(mrun0 - mnew);
        lrun0 = lrun0 * sc + rsum;  mrun0 = mnew;
        const uint32_t pr = pb_cur + (uint32_t)(w * 32 + l15) * PR + (uint32_t)g * 8u;
        *(half4v*)(smem + pr)       = h0;
        *(half4v*)(smem + pr + 32u) = h1;
        if (g == 0) *(float*)(smem + sc_cur + (uint32_t)(w * 32 + l15) * 4u) = sc;
      }
      /* softmax qh1 (q = w*32 + 16 + l15) */
      {
        float tm = -3.0e38f;
#pragma unroll
        for (int r = 0; r < 4; ++r) tm = fmaxf(tm, fmaxf(st10[r], st11[r]));
        tm = fmaxf(tm, __shfl_xor(tm, 16));
        tm = fmaxf(tm, __shfl_xor(tm, 32));
        const float mnew = fmaxf(mrun1, tm);
        float rsum = 0.f;
        half4v h0, h1;
#pragma unroll
        for (int r = 0; r < 4; ++r) {
          const float e0 = __expf(st10[r] - mnew); rsum += e0; h0[r] = (_Float16)e0;
          const float e1 = __expf(st11[r] - mnew); rsum += e1; h1[r] = (_Float16)e1;
        }
        rsum += __shfl_xor(rsum, 16);
        rsum += __shfl_xor(rsum, 32);
        const float sc = __expf(mrun1 - mnew);
        lrun1 = lrun1 * sc + rsum;  mrun1 = mnew;
        const uint32_t pr = pb_cur + (uint32_t)(w * 32 + 16 + l15) * PR + (uint32_t)g * 8u;
        *(half4v*)(smem + pr)       = h0;
        *(half4v*)(smem + pr + 32u) = h1;
        if (g == 0) *(float*)(smem + sc_cur + (uint32_t)(w * 32 + 16 + l15) * 4u) = sc;
      }
    }

    if (!USE_WS && it + 1 < NITER && w >= 2) {
      const float* ybt = yb + (size_t)(it + 1) * TBLK * DD;
#pragma unroll
      for (int i = 0; i < 6; ++i) {
        const int row = (w - 2) + 6 * i;
        if (row < 32) {
          const float* p = ybt + row * DD + lane * 8;
          f32x4 f0 = *(const f32x4*)p, f1 = *(const f32x4*)(p + 4);
          half8v h;
          h[0]=(_Float16)f0[0]; h[1]=(_Float16)f0[1]; h[2]=(_Float16)f0[2]; h[3]=(_Float16)f0[3];
          h[4]=(_Float16)f1[0]; h[5]=(_Float16)f1[1]; h[6]=(_Float16)f1[2]; h[7]=(_Float16)f1[3];
          *(half8v*)(smem + yb_next + (uint32_t)row * RSB + (uint32_t)lane * 16u) = h;
        }
      }
    }

    /* all 8 waves: PV(it-1) on disjoint 64-d slice */
    if (it > 0) pv_step(yb_prev, pb_prev, sc_prev);

    __syncthreads();
  }

  /* final PV(63): P buf 1, scale buf 1, y buf (63%3)=0 */
  pv_step(0u, POFF + PSZ, SCOFF + 256u);

  if (w < 2 && g == 0) {
    *(float*)(smem + LIOFF + (uint32_t)(w * 32 + l15) * 4u)        = 1.0f / lrun0;
    *(float*)(smem + LIOFF + (uint32_t)(w * 32 + 16 + l15) * 4u)   = 1.0f / lrun1;
  }
  __syncthreads();

#pragma unroll
  for (int qq = 0; qq < 4; ++qq) {
    const f32x4 iv = *(const f32x4*)(smem + LIOFF + (uint32_t)(qq * 16 + 4 * g) * 4u);
#pragma unroll
    for (int dtl = 0; dtl < 4; ++dtl) {
#pragma unroll
      for (int r = 0; r < 4; ++r) {
        const int q = qbase + qq * 16 + 4 * g + r;
        outb[(size_t)q * (2 * DD) + DD + w * 64 + dtl * 16 + l15] = acc[qq][dtl][r] * iv[r];
      }
    }
  }
}

extern "C" void kernel_launch(void* const* d_in, const int* in_sizes, int n_in,
                              void* d_out, int out_size, void* d_ws, size_t ws_size,
                              hipStream_t stream) {
  (void)in_sizes; (void)n_in; (void)out_size;
  const float* x = (const float*)d_in[0];
  const float* y = (const float*)d_in[1];
  float* out = (float*)d_out;
  static_assert(LDS_BYTES <= 160 * 1024, "LDS over budget");
  const bool use_ws = (ws_size >= YH_BYTES);
  if (use_ws) {
    _Float16* yh = (_Float16*)d_ws;
    hipLaunchKernelGGL(convert_y, dim3(4096), dim3(256), 0, stream, y, yh);
    hipFuncSetAttribute((const void*)attn_fused<true>,
                        hipFuncAttributeMaxDynamicSharedMemorySize, LDS_BYTES);
    hipLaunchKernelGGL((attn_fused<true>), dim3((SXX / QBLK) * NB), dim3(512),
                       LDS_BYTES, stream, x, y, yh, out);
  } else {
    hipFuncSetAttribute((const void*)attn_fused<false>,
                        hipFuncAttributeMaxDynamicSharedMemorySize, LDS_BYTES);
    hipLaunchKernelGGL((attn_fused<false>), dim3((SXX / QBLK) * NB), dim3(512),
                       LDS_BYTES, stream, x, y, nullptr, out);
  }
}

// Round 13
// 171.033 us; speedup vs baseline: 1.5189x; 1.5189x over previous
//
#include <hip/hip_runtime.h>
#include <stdint.h>

typedef _Float16 half4v __attribute__((ext_vector_type(4)));
typedef _Float16 half8v __attribute__((ext_vector_type(8)));
typedef float    f32x4  __attribute__((ext_vector_type(4)));
typedef __attribute__((address_space(3))) void       lds_void;
typedef const __attribute__((address_space(1))) void g_void;

#define NB 8
#define SXX 2048
#define DD 512
#define QBLK 64
#define TBLK 64
#define NITER 32

/* y tile: row-major fp16, 1024 B rows, XOR-swizzled (T2):
   element (row,d) lives at byte row*1024 + ((2*d) ^ ((row&7)<<4)).
   Staged via global_load_lds with PRE-SWIZZLED per-lane global source
   (LDS dest linear, m173 / rule-21 pattern).  QK b128 column-slice reads
   become bank-balanced (8 lanes per 16B window per 8-row stripe). */
#define RSB 1024u
#define BUFSZ (64u * RSB)          /* 65536 */
#define POFF  (2u * BUFSZ)         /* 131072: P[64 q][64 t] fp16, row 136 B */
#define PR    136u
#define SCOFF (POFF + 64u * PR)    /* 139776: per-q scale f32[64] */
#define TMOFF (SCOFF + 256u)       /* 140032: per-(half,q) tile-max f32[2][64] */
#define LOFF  (TMOFF + 512u)       /* 140544: per-(half,q) l f32[2][64] */
#define LDS_BYTES 141056
#define YH_BYTES (8ull * 2048ull * 512ull * 2ull)   /* 16 MiB fp16 y */

__global__ __launch_bounds__(256)
void convert_y(const float* __restrict__ y, _Float16* __restrict__ yh) {
  const int i = (blockIdx.x * 256 + threadIdx.x) * 8;
  f32x4 f0 = *(const f32x4*)(y + i);
  f32x4 f1 = *(const f32x4*)(y + i + 4);
  half8v h;
  h[0]=(_Float16)f0[0]; h[1]=(_Float16)f0[1]; h[2]=(_Float16)f0[2]; h[3]=(_Float16)f0[3];
  h[4]=(_Float16)f1[0]; h[5]=(_Float16)f1[1]; h[6]=(_Float16)f1[2]; h[7]=(_Float16)f1[3];
  *(half8v*)(yh + i) = h;
}

template <bool USE_WS>
__global__ __launch_bounds__(512, 2)
void attn_fused(const float* __restrict__ x, const float* __restrict__ y,
                const _Float16* __restrict__ yh, float* __restrict__ out) {
  extern __shared__ char smem[];
  const int bid   = blockIdx.x;
  const int b     = bid & 7;      /* one batch per XCD -> yh batch L2-resident */
  const int qtile = bid >> 3;
  const int tid   = threadIdx.x;
  const int w     = tid >> 6;     /* 0..7 */
  const int lane  = tid & 63;
  const int l15   = lane & 15;
  const int g     = lane >> 4;
  const int qw    = w & 3;        /* q-subtile (16 rows) for QK */
  const int th    = w >> 2;       /* t-half (32 t) for QK */

  const float*    xb  = x + (size_t)b * SXX * DD;
  const float*    yb  = y + (size_t)b * SXX * DD;
  const _Float16* yhb = USE_WS ? (yh + (size_t)b * SXX * DD) : nullptr;
  float* outb = out + (size_t)b * SXX * (2 * DD);
  const int qbase = qtile * QBLK;

  /* async-stage tile 0 into buf0 (pre-swizzled global source) */
  if (USE_WS) {
#pragma unroll
    for (int i = 0; i < 8; ++i) {
      const int row = w * 8 + i;
      const uint32_t so = ((uint32_t)lane * 16u) ^ ((uint32_t)(row & 7) << 4);
      __builtin_amdgcn_global_load_lds((g_void*)((const char*)(yhb + row * DD) + so),
                                       (lds_void*)(smem + (uint32_t)row * RSB), 16, 0, 0);
    }
  }

  /* ---- out[:, :512] = x (exact fp32 copy) ---- */
  {
    const f32x4* src = (const f32x4*)(xb + (size_t)qbase * DD);
    for (int i = tid; i < QBLK * (DD / 4); i += 512) {
      f32x4 v = src[i];
      *(f32x4*)(outb + (size_t)(qbase + (i >> 7)) * (2 * DD) + (i & 127) * 4) = v;
    }
  }

  /* ---- Q fragments (fp16), B-operand of 16x16x32 ---- */
  half8v bq[16];
  {
    const float* xr = xb + (size_t)(qbase + qw * 16 + l15) * DD;
#pragma unroll
    for (int c = 0; c < 16; ++c) {
      const int d0 = c * 32 + g * 8;
      f32x4 f0 = *(const f32x4*)(xr + d0);
      f32x4 f1 = *(const f32x4*)(xr + d0 + 4);
      half8v h;
      h[0] = (_Float16)f0[0]; h[1] = (_Float16)f0[1];
      h[2] = (_Float16)f0[2]; h[3] = (_Float16)f0[3];
      h[4] = (_Float16)f1[0]; h[5] = (_Float16)f1[1];
      h[6] = (_Float16)f1[2]; h[7] = (_Float16)f1[3];
      bq[c] = h;
    }
  }

  if (!USE_WS) {
#pragma unroll
    for (int k = 0; k < 8; ++k) {
      const int u = tid + k * 512;
      const int t = u >> 6, c8 = u & 63;
      const float* p = yb + t * DD + c8 * 8;
      f32x4 f0 = *(const f32x4*)p, f1 = *(const f32x4*)(p + 4);
      half8v h;
      h[0]=(_Float16)f0[0]; h[1]=(_Float16)f0[1]; h[2]=(_Float16)f0[2]; h[3]=(_Float16)f0[3];
      h[4]=(_Float16)f1[0]; h[5]=(_Float16)f1[1]; h[6]=(_Float16)f1[2]; h[7]=(_Float16)f1[3];
      const uint32_t bo = ((uint32_t)c8 * 16u) ^ ((uint32_t)(t & 7) << 4);
      *(half8v*)(smem + (uint32_t)t * RSB + bo) = h;
    }
  }

  f32x4 acc[4][4];   /* [qq][dtl]: a[qbase+qq*16+4g+r][w*64+dtl*16+l15] */
#pragma unroll
  for (int i = 0; i < 4; ++i)
#pragma unroll
    for (int j = 0; j < 4; ++j) acc[i][j] = (f32x4){0.f, 0.f, 0.f, 0.f};
  float mrun = -3.0e38f, lrun = 0.0f;

  __syncthreads();

  for (int it = 0; it < NITER; ++it) {
    const uint32_t cb  = (uint32_t)(it & 1) * BUFSZ;
    const uint32_t nb2 = cb ^ BUFSZ;

    /* async-issue next tile into the other buffer */
    if (USE_WS && it + 1 < NITER) {
      const _Float16* src = yhb + (size_t)(it + 1) * TBLK * DD;
#pragma unroll
      for (int i = 0; i < 8; ++i) {
        const int row = w * 8 + i;
        const uint32_t so = ((uint32_t)lane * 16u) ^ ((uint32_t)(row & 7) << 4);
        __builtin_amdgcn_global_load_lds((g_void*)((const char*)(src + row * DD) + so),
                                         (lds_void*)(smem + nb2 + (uint32_t)row * RSB), 16, 0, 0);
      }
    }

    /* ---- QK^T swapped, t-split: wave (qw,th) does 16q x 32t.
       A-row = th*32 + tt*16 + l15  (row&7 == l15&7), swizzled column read.
       C: lane holds q = l15 (col), t-row = th*32 + 16tt + 4g + r. ---- */
    {
      const uint32_t qkmask = ((uint32_t)(l15 & 7)) << 4;
      f32x4 st[2];
      st[0] = (f32x4){0.f, 0.f, 0.f, 0.f};
      st[1] = (f32x4){0.f, 0.f, 0.f, 0.f};
#pragma unroll
      for (int c = 0; c < 16; ++c) {
        const uint32_t db = (64u * (uint32_t)c + 16u * (uint32_t)g) ^ qkmask;
#pragma unroll
        for (int tt = 0; tt < 2; ++tt) {
          const half8v af =
              *(const half8v*)(smem + cb + (uint32_t)(th * 32 + tt * 16 + l15) * RSB + db);
          st[tt] = __builtin_amdgcn_mfma_f32_16x16x32_f16(af, bq[c], st[tt], 0, 0, 0);
        }
      }

      /* ---- tile-max over this wave's 32 t, exchange with partner half ---- */
      float tmax = -3.0e38f;
#pragma unroll
      for (int tt = 0; tt < 2; ++tt)
#pragma unroll
        for (int r = 0; r < 4; ++r) tmax = fmaxf(tmax, st[tt][r]);
      tmax = fmaxf(tmax, __shfl_xor(tmax, 16));
      tmax = fmaxf(tmax, __shfl_xor(tmax, 32));
      if (g == 0) ((float*)(smem + TMOFF))[th * 64 + qw * 16 + l15] = tmax;
      __syncthreads();   /* B-mid: tile-maxes visible */
      const float tm0 = ((float*)(smem + TMOFF))[qw * 16 + l15];
      const float tm1 = ((float*)(smem + TMOFF))[64 + qw * 16 + l15];
      const float mnew = fmaxf(mrun, fmaxf(tm0, tm1));   /* common across partners */

      float pvv[8];
      float rsum = 0.f;
#pragma unroll
      for (int tt = 0; tt < 2; ++tt)
#pragma unroll
        for (int r = 0; r < 4; ++r) {
          const float e = __expf(st[tt][r] - mnew);
          pvv[tt * 4 + r] = e;
          rsum += e;
        }
      rsum += __shfl_xor(rsum, 16);
      rsum += __shfl_xor(rsum, 32);
      const float scale = __expf(mrun - mnew);   /* identical for both partners */
      lrun = lrun * scale + rsum;
      mrun = mnew;

      /* write P[q = qw*16+l15][t = th*32+16tt+4g+r]; scale once per q */
#pragma unroll
      for (int tt = 0; tt < 2; ++tt) {
        half4v hv;
        hv[0] = (_Float16)pvv[tt * 4 + 0]; hv[1] = (_Float16)pvv[tt * 4 + 1];
        hv[2] = (_Float16)pvv[tt * 4 + 2]; hv[3] = (_Float16)pvv[tt * 4 + 3];
        *(half4v*)(smem + POFF + (uint32_t)(qw * 16 + l15) * PR +
                   (uint32_t)(th * 64 + tt * 32) + (uint32_t)g * 8u) = hv;
      }
      if (th == 0 && g == 0) ((float*)(smem + SCOFF))[qw * 16 + l15] = scale;
    }

    if (!USE_WS && it + 1 < NITER) {
      const float* ybt = yb + (size_t)(it + 1) * TBLK * DD;
#pragma unroll
      for (int k = 0; k < 8; ++k) {
        const int u = tid + k * 512;
        const int t = u >> 6, c8 = u & 63;
        const float* p = ybt + t * DD + c8 * 8;
        f32x4 f0 = *(const f32x4*)p, f1 = *(const f32x4*)(p + 4);
        half8v h;
        h[0]=(_Float16)f0[0]; h[1]=(_Float16)f0[1]; h[2]=(_Float16)f0[2]; h[3]=(_Float16)f0[3];
        h[4]=(_Float16)f1[0]; h[5]=(_Float16)f1[1]; h[6]=(_Float16)f1[2]; h[7]=(_Float16)f1[3];
        const uint32_t bo = ((uint32_t)c8 * 16u) ^ ((uint32_t)(t & 7) << 4);
        *(half8v*)(smem + nb2 + (uint32_t)t * RSB + bo) = h;
      }
    }

    __syncthreads();   /* B1: P/scale visible, staging drained */

    /* ---- PV: all 8 waves, disjoint 64-d slices ---- */
    {
      /* unconditional rescale (scale==1 when no new max) */
#pragma unroll
      for (int qq = 0; qq < 4; ++qq) {
        const f32x4 s4 = *(const f32x4*)(smem + SCOFF + (uint32_t)(qq * 16 + 4 * g) * 4u);
#pragma unroll
        for (int dtl = 0; dtl < 4; ++dtl) {
          acc[qq][dtl][0] *= s4[0]; acc[qq][dtl][1] *= s4[1];
          acc[qq][dtl][2] *= s4[2]; acc[qq][dtl][3] *= s4[3];
        }
      }
      __builtin_amdgcn_sched_barrier(0);

      /* batch-issue ALL PV LDS reads, then one full wait */
      half4v palo[4][2], pahi[4][2];
      const uint32_t pb = POFF + (uint32_t)l15 * PR + (uint32_t)g * 8u;
#pragma unroll
      for (int qq = 0; qq < 4; ++qq)
#pragma unroll
        for (int ch = 0; ch < 2; ++ch) {
          const uint32_t a = pb + (uint32_t)qq * (16u * PR) + (uint32_t)ch * 64u;
          asm volatile("ds_read_b64 %0, %1" : "=v"(palo[qq][ch]) : "v"(a));
          asm volatile("ds_read_b64 %0, %1" : "=v"(pahi[qq][ch]) : "v"(a + 32u));
        }
      /* V tr-reads: row r = 4g+(l15>>2) (+32*(fr>>2), +16 for hi);
         (r&7) invariant -> single per-lane mask; per-access XOR on the
         in-row byte (bits 4-6 overlap the dtl*32 term). */
      half4v blo[8], bhi[8];
      const uint32_t r0 = (uint32_t)(4 * g + (l15 >> 2));
      const uint32_t trmask = (r0 & 7u) << 4;
      const uint32_t inner0 = (uint32_t)(l15 & 3) * 8u + (uint32_t)w * 128u;
#pragma unroll
      for (int fr = 0; fr < 8; ++fr) {
        const uint32_t rowb = cb + (r0 + (uint32_t)(fr >> 2) * 32u) * RSB;
        const uint32_t bo = (inner0 + (uint32_t)(fr & 3) * 32u) ^ trmask;
        asm volatile("ds_read_b64_tr_b16 %0, %1" : "=v"(blo[fr]) : "v"(rowb + bo));
        asm volatile("ds_read_b64_tr_b16 %0, %1" : "=v"(bhi[fr]) : "v"(rowb + 16u * RSB + bo));
      }
      asm volatile("s_waitcnt lgkmcnt(0)" ::: "memory");
      __builtin_amdgcn_sched_barrier(0);

#pragma unroll
      for (int fr = 0; fr < 8; ++fr) {
        const half8v b8 = __builtin_shufflevector(blo[fr], bhi[fr], 0, 1, 2, 3, 4, 5, 6, 7);
        const int ch = fr >> 2, dtl = fr & 3;
#pragma unroll
        for (int qq = 0; qq < 4; ++qq) {
          const half8v pa = __builtin_shufflevector(palo[qq][ch], pahi[qq][ch],
                                                    0, 1, 2, 3, 4, 5, 6, 7);
          acc[qq][dtl] = __builtin_amdgcn_mfma_f32_16x16x32_f16(pa, b8, acc[qq][dtl], 0, 0, 0);
        }
      }
    }
    __syncthreads();   /* B2: PV reads of P/cbuf done */
  }

  /* ---- epilogue: l = l(th=0) + l(th=1), then store a into out[:, 512:] ---- */
  if (g == 0) ((float*)(smem + LOFF))[th * 64 + qw * 16 + l15] = lrun;
  __syncthreads();
#pragma unroll
  for (int qq = 0; qq < 4; ++qq) {
    const f32x4 l0 = *(const f32x4*)(smem + LOFF + (uint32_t)(qq * 16 + 4 * g) * 4u);
    const f32x4 l1 = *(const f32x4*)(smem + LOFF + 256u + (uint32_t)(qq * 16 + 4 * g) * 4u);
    f32x4 iv;
#pragma unroll
    for (int r = 0; r < 4; ++r) iv[r] = 1.0f / (l0[r] + l1[r]);
#pragma unroll
    for (int dtl = 0; dtl < 4; ++dtl) {
#pragma unroll
      for (int r = 0; r < 4; ++r) {
        const int q = qbase + qq * 16 + 4 * g + r;
        outb[(size_t)q * (2 * DD) + DD + w * 64 + dtl * 16 + l15] = acc[qq][dtl][r] * iv[r];
      }
    }
  }
}

extern "C" void kernel_launch(void* const* d_in, const int* in_sizes, int n_in,
                              void* d_out, int out_size, void* d_ws, size_t ws_size,
                              hipStream_t stream) {
  (void)in_sizes; (void)n_in; (void)out_size;
  const float* x = (const float*)d_in[0];
  const float* y = (const float*)d_in[1];
  float* out = (float*)d_out;
  static_assert(LDS_BYTES <= 160 * 1024, "LDS over budget");
  const bool use_ws = (ws_size >= YH_BYTES);
  if (use_ws) {
    _Float16* yh = (_Float16*)d_ws;
    hipLaunchKernelGGL(convert_y, dim3(4096), dim3(256), 0, stream, y, yh);
    hipFuncSetAttribute((const void*)attn_fused<true>,
                        hipFuncAttributeMaxDynamicSharedMemorySize, LDS_BYTES);
    hipLaunchKernelGGL((attn_fused<true>), dim3((SXX / QBLK) * NB), dim3(512),
                       LDS_BYTES, stream, x, y, yh, out);
  } else {
    hipFuncSetAttribute((const void*)attn_fused<false>,
                        hipFuncAttributeMaxDynamicSharedMemorySize, LDS_BYTES);
    hipLaunchKernelGGL((attn_fused<false>), dim3((SXX / QBLK) * NB), dim3(512),
                       LDS_BYTES, stream, x, y, nullptr, out);
  }
}